// Round 1
// 126.506 us; speedup vs baseline: 1.0422x; 1.0422x over previous
//
#include <hip/hip_runtime.h>
#include <hip/hip_bf16.h>
#include <math.h>
#include <stdint.h>

// Problem: B=64, SQ=64, SD=512, H=128
#define BB 64
#define SQN 64
#define SDN 512
#define HH 128

typedef __attribute__((ext_vector_type(8))) short bf16x8;     // 8 bf16 = 4 VGPRs
typedef __attribute__((ext_vector_type(16))) float f32x16;    // 16 acc regs

__device__ __forceinline__ short f2bf(float f) {
  union { float f; unsigned u; } x; x.f = f;
  unsigned r = x.u + 0x7fffu + ((x.u >> 16) & 1u);   // RNE
  return (short)(r >> 16);
}

__device__ __forceinline__ void gl_lds16(const short* g, short* l) {
  __builtin_amdgcn_global_load_lds(
      (const __attribute__((address_space(1))) unsigned int*)g,
      (__attribute__((address_space(3))) unsigned int*)l, 16, 0, 0);
}

// ---- per-(b,side) mask compaction: perm[j] = j-th valid t, padded to 128 ----
// Dropping masked rows is exact under the masked-zero argument: maxsim inits
// its running max at 0 and true max over valid t is >= 0 w.p. 1-2^-256.
// NEW: also emits nvalid (exact run length) so maxsim can trim the last
// chunk's t-tiles to ceil(valid/32) instead of computing 4 full tiles.
__global__ __launch_bounds__(64)
void compact_meta(const int* __restrict__ mp, const int* __restrict__ mn,
                  int* __restrict__ perm, int* __restrict__ nchunks,
                  int* __restrict__ nvalid) {
  const int b = blockIdx.x, side = blockIdx.y;
  const int* mask = side ? mn : mp;
  const int ln = threadIdx.x;
  const int base = (side * BB + b) * SDN;
  int run = 0;
  #pragma unroll
  for (int it = 0; it < SDN / 64; ++it) {
    int t = it * 64 + ln;
    int m = mask[b * SDN + t];
    unsigned long long bal = __ballot(m != 0);
    int pos = run + __popcll(bal & ((1ull << ln) - 1ull));
    if (m) perm[base + pos] = t;
    run += (int)__popcll(bal);
  }
  int pad = (run + 127) & ~127;
  for (int j = run + ln; j < pad; j += 64) perm[base + j] = -1;
  if (ln == 0) {
    nchunks[side * BB + b] = pad >> 7;
    nvalid[side * BB + b]  = run;
  }
}

// ---- fp32 -> bf16 convert, wide grid: q (contiguous) + d (gather via perm) ----
// NEW: rows beyond the pad boundary (j >= nchunks*128) are never staged by
// maxsim -> skip them entirely (saves ~6.5 MB of writes and avoids reading
// poison perm entries beyond the pad).
__global__ __launch_bounds__(256)
void convert_all(const float* __restrict__ q, const float* __restrict__ dp,
                 const float* __restrict__ dn, const int* __restrict__ perm,
                 const int* __restrict__ nchunks,
                 short* __restrict__ oq, short* __restrict__ od) {
  const int D_BLOCKS = (2 * BB * SDN) / 8;   // 8192 (8 rows/block, 32 thr/row)
  if (blockIdx.x < D_BLOCKS) {
    int gid = blockIdx.x * 8 + (threadIdx.x >> 5);   // compacted row id
    int l32 = threadIdx.x & 31;
    int bs = gid >> 9;            // side*64+b
    int j  = gid & 511;
    if (j >= (nchunks[bs] << 7)) return;   // beyond pad: never read by maxsim
    int side = bs >> 6, b = bs & 63;
    int src_t = perm[bs * SDN + j];        // j < pad: always written (valid or -1)
    const float* srcmat = side ? dn : dp;
    float4 v = make_float4(0.f, 0.f, 0.f, 0.f);
    if (src_t >= 0)
      v = ((const float4*)(srcmat + ((size_t)b * SDN + src_t) * HH))[l32];
    short4 o; o.x = f2bf(v.x); o.y = f2bf(v.y); o.z = f2bf(v.z); o.w = f2bf(v.w);
    *(short4*)&od[((size_t)bs * SDN + j) * HH + l32 * 4] = o;
  } else {
    int i = (blockIdx.x - D_BLOCKS) * 256 + threadIdx.x;  // float4 index, exact
    float4 v = ((const float4*)q)[i];
    short4 o; o.x = f2bf(v.x); o.y = f2bf(v.y); o.z = f2bf(v.z); o.w = f2bf(v.w);
    *(short4*)&oq[i * 4] = o;
  }
}

// Persistent maxsim: grid 512 = (16 a-slices x 32 b-groups), 2 blocks/CU
// co-resident, ONE dispatch round. Each block streams 4 consecutive bs
// values through one double-buffered pipeline (prefetch crosses bs
// boundaries) -> prologue paid once, no round raggedness.
//
// NEW (this round):
//  1. XCD swizzle: linear block id % 8 picks the XCD (round-robin dispatch).
//     Remap so each XCD owns 4 whole bgroups x 16 a-slices: the 16 blocks
//     that re-read the SAME d-chunks now share one L2 (~4 MB working set
//     fits the 4 MB per-XCD L2) instead of being scattered over all 8.
//     Bijective: lid -> (xcd=lid&7, slot=lid>>3) -> bgroup=xcd+8*(slot>>4),
//     aslc=slot&15.
//  2. Last-chunk t-tile trim: compute only ceil((valid-128*tc)/32) of the 4
//     32-row t-tiles in the final chunk of each bs. Skipped tiles are
//     all-zero rows (convert wrote zeros up to pad), whose max contribution
//     is 0 = rmax's init -> bit-exact. Cuts MFMA work ~15% (E[pad128]=318
//     rows vs E[pad32]=260 for valid~256).
//
// MFMA operand order: mfma(dfrag, qfrag) -> C[m=t][n=s]; max-over-t is an
// in-register 16-reg v_max tree per tile; per-bs finalize is 7 shuffles.
// d_lds per buffer: 128 rows x 128 bf16, 16B chunks XOR-swizzled
// (chunk c of row r at c^(r&15)): staging + ds_read_b128 conflict-free.
__global__ __launch_bounds__(256, 2)
void maxsim_kernel(const short* __restrict__ qb,
                   const short* __restrict__ dc,
                   const int* __restrict__ nchunks,
                   const int* __restrict__ nvalid,
                   float* __restrict__ scores) {
  const int lid  = blockIdx.x + 16 * blockIdx.y;   // 0..511
  const int xcd  = lid & 7;
  const int slot = lid >> 3;                        // 0..63 within XCD
  const int aslc = slot & 15;
  const int bs0  = (xcd + 8 * (slot >> 4)) * 4;     // bgroup*4

  __shared__ __align__(16) short d_lds[2][128 * 128];  // 2 x 32 KB

  const int tid = threadIdx.x;
  const int ln  = tid & 63;
  const int w   = tid >> 6;
  const int l31 = ln & 31;
  const int kh  = ln >> 5;
  const int a   = aslc * 4 + w;  // this wave's query (owns all 64 s)

  int nchv[4], nvv[4];
  #pragma unroll
  for (int i = 0; i < 4; ++i) {
    nchv[i] = nchunks[bs0 + i];   // block-uniform
    nvv[i]  = nvalid[bs0 + i];
  }

  // ---- q as B-operand (persistent, from L2/LLC): n = half*32+l31, k = kc*16+kh*8 ----
  bf16x8 qfrag[2][8];
  #pragma unroll
  for (int half = 0; half < 2; ++half) {
    const short* qrow = qb + ((size_t)a * SQN + half * 32 + l31) * HH + kh * 8;
    #pragma unroll
    for (int kc = 0; kc < 8; ++kc)
      qfrag[half][kc] = *(const bf16x8*)(qrow + kc * 16);
  }

  float rmaxh[2] = {0.f, 0.f};   // masked-zero trick: true max >= 0

  // ---- stage chunk (bs0, 0) into buffer 0 ----
  {
    const short* dsrc = dc + (size_t)bs0 * SDN * HH;
    #pragma unroll
    for (int it = 0; it < 8; ++it) {
      int f = it * 256 + tid;
      int row = f >> 4;
      int c = (f & 15) ^ (row & 15);
      gl_lds16(&dsrc[row * HH + c * 8], &d_lds[0][(it * 256 + w * 64) * 8]);
    }
  }
  __syncthreads();

  int bi = 0, tc = 0, buf = 0;
  for (;;) {
    // next flat chunk (possibly first chunk of next bs)
    int nbi = bi, ntc = tc + 1;
    if (ntc == nchv[bi]) { ntc = 0; nbi = bi + 1; }
    const bool hn = (nbi < 4);

    // ---- issue prefetch BEFORE compute (drain lands after MFMA phase) ----
    if (hn) {
      const short* dsrc = dc + ((size_t)(bs0 + nbi) * SDN + ntc * 128) * HH;
      short* dst = &d_lds[buf ^ 1][0];
      #pragma unroll
      for (int it = 0; it < 8; ++it) {
        int f = it * 256 + tid;
        int row = f >> 4;
        int c = (f & 15) ^ (row & 15);
        gl_lds16(&dsrc[row * HH + c * 8], &dst[(it * 256 + w * 64) * 8]);
      }
    }

    // ---- compute: up to 4 t-tiles x 8 kc x 2 s-halves; C[m=t][n=s] ----
    // Last chunk of a bs: only ceil((valid - tc*128)/32) tiles are non-zero.
    const int ntt = (tc == nchv[bi] - 1)
                        ? ((nvv[bi] - (tc << 7) + 31) >> 5)   // 1..4, uniform
                        : 4;
    const short* bufp = &d_lds[buf][0];
    #pragma unroll
    for (int tt = 0; tt < 4; ++tt) {
      if (tt < ntt) {
        int trow = tt * 32 + l31;
        int tm = trow & 15;
        const short* bbase = &bufp[trow * HH];
        f32x16 acc0 = {0,0,0,0,0,0,0,0,0,0,0,0,0,0,0,0};
        f32x16 acc1 = {0,0,0,0,0,0,0,0,0,0,0,0,0,0,0,0};
        #pragma unroll
        for (int kc = 0; kc < 8; ++kc) {
          int c = (kc * 2 + kh) ^ tm;
          bf16x8 dfrag = *(const bf16x8*)&bbase[c * 8];  // A: m = t = trow
          acc0 = __builtin_amdgcn_mfma_f32_32x32x16_bf16(dfrag, qfrag[0][kc], acc0, 0, 0, 0);
          acc1 = __builtin_amdgcn_mfma_f32_32x32x16_bf16(dfrag, qfrag[1][kc], acc1, 0, 0, 0);
        }
        // C: col = l31 = s (within half), rows = 16 t's of this lane's kh group
        float m0 = acc0[0], m1 = acc1[0];
        #pragma unroll
        for (int r = 1; r < 16; ++r) {
          m0 = fmaxf(m0, acc0[r]);
          m1 = fmaxf(m1, acc1[r]);
        }
        rmaxh[0] = fmaxf(rmaxh[0], m0);
        rmaxh[1] = fmaxf(rmaxh[1], m1);
      }
    }

    // ---- finished bs(bi)? finalize: cross-kh max, then sum over s ----
    if (ntc == 0) {
      float v0 = fmaxf(rmaxh[0], __shfl_xor(rmaxh[0], 32));  // merge kh t-halves
      float v1 = fmaxf(rmaxh[1], __shfl_xor(rmaxh[1], 32));
      float s = v0 + v1;                 // s = l31 and s = 32+l31
      s += __shfl_xor(s, 1);  s += __shfl_xor(s, 2);  s += __shfl_xor(s, 4);
      s += __shfl_xor(s, 8);  s += __shfl_xor(s, 16);
      if (ln == 0) scores[(size_t)a * (2 * BB) + bs0 + bi] = s;
      rmaxh[0] = 0.f; rmaxh[1] = 0.f;
    }

    // barrier: all waves done reading buf before re-stage; drains prefetch
    __syncthreads();
    if (!hn) break;
    bi = nbi; tc = ntc; buf ^= 1;
  }
}

// single block: loss = mean_a [ logsumexp(scores[a,:]) - scores[a,a] ]
__global__ __launch_bounds__(1024)
void loss_kernel(const float* __restrict__ scores, float* __restrict__ out) {
  __shared__ float part[16];
  const int tid = threadIdx.x;
  const int ln = tid & 63;
  const int w  = tid >> 6;        // 16 waves; wave w handles rows 4w..4w+3
  float acc = 0.f;
  #pragma unroll
  for (int i = 0; i < 4; ++i) {
    int r = w * 4 + i;
    float v0 = scores[r * 128 + ln];
    float v1 = scores[r * 128 + 64 + ln];
    float mx = fmaxf(v0, v1);
    #pragma unroll
    for (int off = 32; off >= 1; off >>= 1) mx = fmaxf(mx, __shfl_xor(mx, off));
    float e = __expf(v0 - mx) + __expf(v1 - mx);
    #pragma unroll
    for (int off = 32; off >= 1; off >>= 1) e += __shfl_xor(e, off);
    float lse = mx + __logf(e);
    float diag = __shfl(v0, r);   // r < 64, diagonal lives in v0 at lane r
    acc += lse - diag;
  }
  if (ln == 0) part[w] = acc;
  __syncthreads();
  if (w == 0) {
    float v = (ln < 16) ? part[ln] : 0.f;
    #pragma unroll
    for (int off = 8; off >= 1; off >>= 1) v += __shfl_xor(v, off);
    if (ln == 0) out[0] = v * (1.0f / 64.0f);
  }
}

extern "C" void kernel_launch(void* const* d_in, const int* in_sizes, int n_in,
                              void* d_out, int out_size, void* d_ws, size_t ws_size,
                              hipStream_t stream) {
  const float* q        = (const float*)d_in[0];
  const float* d_pos    = (const float*)d_in[1];
  const float* d_neg    = (const float*)d_in[2];
  const int*   mask_pos = (const int*)d_in[3];
  const int*   mask_neg = (const int*)d_in[4];

  // ws layout: q_bf 1 MB | d_c 16 MB | perm 256 KB | nchunks | nvalid | scores
  short* q_bf = (short*)d_ws;                                  // 524288 shorts
  short* d_c  = q_bf + (size_t)BB * SQN * HH;                  // 8388608 shorts
  int*   perm = (int*)(d_c + (size_t)2 * BB * SDN * HH);       // 65536 ints
  int*   nchunks = perm + 2 * BB * SDN;                        // 128 ints
  int*   nvalid  = nchunks + 128;                              // 128 ints
  float* scores  = (float*)(nvalid + 128);                     // 8192 floats

  compact_meta<<<dim3(BB, 2), 64, 0, stream>>>(mask_pos, mask_neg, perm,
                                               nchunks, nvalid);

  const int D_BLOCKS = (2 * BB * SDN) / 8;          // 8192
  const int Q_BLOCKS = (BB * SQN * HH / 4) / 256;   // 512
  convert_all<<<D_BLOCKS + Q_BLOCKS, 256, 0, stream>>>(q, d_pos, d_neg, perm,
                                                       nchunks, q_bf, d_c);

  dim3 grid(16 /*a-slices*/, 32 /*b-groups*/);
  maxsim_kernel<<<grid, 256, 0, stream>>>(q_bf, d_c, nchunks, nvalid, scores);

  loss_kernel<<<1, 1024, 0, stream>>>(scores, (float*)d_out);
}